// Round 11
// baseline (136.240 us; speedup 1.0000x reference)
//
#include <hip/hip_runtime.h>
#include <stdint.h>

#define NR 8192
#define DD 128

typedef __attribute__((ext_vector_type(4))) int int32x4;
typedef __attribute__((ext_vector_type(8))) int int32x8;
typedef __attribute__((ext_vector_type(4))) float f32x4;

#ifdef __has_builtin
#if __has_builtin(__builtin_amdgcn_exp2f)
#define EXP2F __builtin_amdgcn_exp2f
#endif
#endif
#ifndef EXP2F
#define EXP2F exp2f
#endif

// exp(10*x) == exp2(x * 10/ln2).  10/ln2 folded into the stored values:
// q = e4m3( sqrt(10/ln2) * normalized ), so every pairwise product (MFMA
// dot, p0 elementwise, diag) is already the exp2 argument.
#define SQK 3.79828255f     // sqrt(10/ln2)
#define SCALE1 0x7F7F7F7F   // e8m0 127 = 2^0 in every byte

// ---- OCP e4m3fn software encode (RNE) / decode (exact) --------------------
__device__ __forceinline__ uint32_t enc_e4m3(float x) {
  uint32_t u = __float_as_uint(x);
  uint32_t s = (u >> 31) << 7;
  float ax = fabsf(x);
  if (ax < 0.015625f) {                 // subnormal target: m * 2^-9
    int m = (int)rintf(ax * 512.0f);    // RNE; 0..8
    return (m >= 8) ? (s | (1u << 3)) : (s | (uint32_t)m);
  }
  uint32_t v = u & 0x7FFFFFFFu;
  v += 0x7FFFFu + ((v >> 20) & 1u);     // RNE to 3 mantissa bits
  int e = (int)((v >> 23) & 255u) - 127;
  uint32_t m3 = (v >> 20) & 7u;
  return s | ((uint32_t)(e + 7) << 3) | m3;   // |x| <= ~2 -> no overflow
}
__device__ __forceinline__ float dec_e4m3(uint32_t b) {
  uint32_t s = b >> 7, e = (b >> 3) & 15u, m = b & 7u;
  float v = e ? __uint_as_float(((e + 120u) << 23) | (m << 20))
              : (float)m * 0.001953125f;      // m * 2^-9
  return s ? -v : v;
}

// ---------------------------------------------------------------------------
// K1: row L2-normalize (fp32), emit e4m3 copies scaled by SQK, diag =
// sum(dequant^2).  Zeroes sums, credit scratch, and d_out.
// ---------------------------------------------------------------------------
__global__ __launch_bounds__(256) void k_normalize(
    const float* __restrict__ u1, const float* __restrict__ u2,
    const float* __restrict__ i1, const float* __restrict__ i2,
    uint8_t* __restrict__ nb, float* __restrict__ diag,
    float* __restrict__ sums, float* __restrict__ scratch, int scrN,
    float* __restrict__ out)
{
  int tid = threadIdx.x;
  int gid = blockIdx.x * 256 + tid;
  if (gid < 6 * NR) sums[gid] = 0.0f;
  if (gid < scrN) scratch[gid] = 0.0f;    // grid covers 2.1M threads >= scrN
  if (gid == 0) out[0] = 0.0f;

  int w = tid >> 6, lane = tid & 63;
  int rowId = blockIdx.x * 4 + w;            // 0..32767
  int mi = rowId >> 13, r = rowId & (NR - 1);
  const float* src = (mi == 0) ? u1 : (mi == 1) ? u2 : (mi == 2) ? i1 : i2;
  const float2 v = *(const float2*)(src + (size_t)r * DD + lane * 2);
  float ss = v.x * v.x + v.y * v.y;
#pragma unroll
  for (int off = 32; off >= 1; off >>= 1) ss += __shfl_xor(ss, off, 64);
  float sc = SQK / fmaxf(sqrtf(ss), 1e-12f);
  uint32_t c0 = enc_e4m3(v.x * sc);
  uint32_t c1 = enc_e4m3(v.y * sc);
  uint8_t* dst = nb + (size_t)mi * NR * DD + (size_t)r * DD + lane * 2;
  *(uint16_t*)dst = (uint16_t)(c0 | (c1 << 8));
  float d0 = dec_e4m3(c0), d1 = dec_e4m3(c1);
  float dd = d0 * d0 + d1 * d1;
#pragma unroll
  for (int off = 32; off >= 1; off >>= 1) dd += __shfl_xor(dd, off, 64);
  if (lane == 0) diag[rowId] = dd;
}

// ---------------------------------------------------------------------------
// K2: MX-fp8 Gram row-sums with UNIFORM diagonal-wrap symmetry.
// Cross jobs (s12u/s12i): full Gram, 32 rb x 8 chunks x 16 tiles = 512 tasks.
// Symmetric jobs (s11/s22): row-block rb covers col-blocks (rb+k)%32,
// k=0..16 (rb<16) / k=0..15 (rb>=16) — every unordered pair exactly once
// (d=1..15 from lower row; d=16 from rb<16; d>16 == 32-d).  Per rb: 4 tasks
// of KQ=17/16 tiles -> 512 uniform tasks.  Grid 1024 = 4 blocks/CU
// (launch_bounds(256,4): VGPR cap 128 >> ~90 used; r4 spill check done).
// Off-diagonal tiles (koff>=4) emit col credits: wave partials -> ldsCol
// (2KB dbuf) -> one wave plain-stores 64 f32 to scratch[sj][rb][col]
// (unique writer, no atomics — r5's 274MB atomic RMW lesson).
// Counted-vmcnt triple-buffer pipeline from r10; lgkmcnt(0) added at the
// barrier for cross-wave ldsCol visibility.
// ---------------------------------------------------------------------------
__global__ __launch_bounds__(256, 4) void k_gram(
    const uint8_t* __restrict__ nb, float* __restrict__ sums,
    float* __restrict__ scratch, int useScratch)
{
  __shared__ alignas(16) uint8_t ldsB[3][64 * DD];   // 3 x 8 KB
  __shared__ float ldsCol[2][4][64];                 // 2 KB credit buffer

  // bijective XCD-chunk swizzle: 1024 = 8 * 128
  int bid = (blockIdx.x & 7) * 128 + (blockIdx.x >> 3);

  int job, rb, q, KQ, nt, sj = 0, cb0;
  bool isSym;
  const int sjobs[4] = {1, 2, 4, 5};
  if (bid < 512) {                       // cross: full 128-tile rows
    isSym = false;
    job = (bid >= 256) ? 3 : 0;
    int r = bid & 255;
    rb = r >> 3;                         // 0..31
    q = r & 7;                           // 8 chunks x 16 tiles
    KQ = 16; nt = 16; cb0 = 0;
  } else {                               // symmetric: diagonal-wrap
    isSym = true;
    int s = bid - 512;
    sj = s >> 7;                         // 0..3
    job = sjobs[sj];
    int idx = s & 127;
    rb = idx >> 2;                       // 0..31
    q = idx & 3;                         // 4 tasks
    KQ = (rb < 16) ? 17 : 16;
    nt = KQ; cb0 = 4 * rb;
  }

  // job -> (A,B,out): 0:(u1,u2) 1:(u1,u1) 2:(u2,u2) 3:(i1,i2) 4:(i1,i1) 5:(i2,i2)
  const int ja[6] = {0, 0, 1, 2, 2, 3};
  const int jb[6] = {1, 0, 1, 3, 2, 3};
  const uint8_t* A = nb + (size_t)ja[job] * NR * DD;
  const uint8_t* B = nb + (size_t)jb[job] * NR * DD;
  float* out = sums + job * NR;

  int tid = threadIdx.x, w = tid >> 6, lane = tid & 63;
  int l15 = lane & 15, lg = lane >> 4;
  int rowBase = rb * 256 + w * 64;

  const char* Bb = (const char*)B;
  char* ldsbase = (char*)&ldsB[0][0];

  // tile jt -> Gram col-tile index (64 cols each), wrap at 128
#define TCOL(jt) ((cb0 + q * KQ + (jt)) & 127)

  // stage one 64-col tile (8KB): linear LDS dest, inverse-swizzled source
#define STAGE(dst, tc)                                                        \
  {                                                                           \
    const char* tbase = Bb + (size_t)(tc) * 8192;                             \
    _Pragma("unroll")                                                         \
    for (int it = 0; it < 2; ++it) {                                          \
      int dbase = it * 4096 + w * 1024;                                       \
      int doff = dbase + lane * 16;                                           \
      int soff = doff ^ (((doff >> 7) & 7) << 4);                             \
      __builtin_amdgcn_global_load_lds(                                       \
          (const __attribute__((address_space(1))) void*)(tbase + soff),      \
          (__attribute__((address_space(3))) void*)((dst) + dbase),           \
          16, 0, 0);                                                          \
    }                                                                         \
  }

#define COMPUTE(bufc, DOCOL, jtv)                                             \
  {                                                                           \
    _Pragma("unroll")                                                         \
    for (int c = 0; c < 4; ++c) {                                             \
      int rr = c * 16 + l15;                                                  \
      int base = rr * 128 + lg * 32;                                          \
      int swz = (rr & 7) << 4;                                                \
      int32x4 blo = *(const int32x4*)((bufc) + (base ^ swz));                 \
      int32x4 bhi = *(const int32x4*)((bufc) + ((base + 16) ^ swz));          \
      int32x8 b8 = __builtin_shufflevector(blo, bhi, 0, 1, 2, 3, 4, 5, 6, 7); \
      float cacc = 0.0f;                                                      \
      _Pragma("unroll")                                                       \
      for (int m = 0; m < 4; ++m) {                                           \
        f32x4 acc = {0.0f, 0.0f, 0.0f, 0.0f};                                 \
        acc = __builtin_amdgcn_mfma_scale_f32_16x16x128_f8f6f4(               \
            af[m], b8, acc, 0, 0, 0, SCALE1, 0, SCALE1);                      \
        _Pragma("unroll")                                                     \
        for (int j = 0; j < 4; ++j) {                                         \
          float v = EXP2F(acc[j]);                                            \
          racc[m][j] += v;                                                    \
          if (DOCOL) cacc += v;                                               \
        }                                                                     \
      }                                                                       \
      if (DOCOL) {                                                            \
        cacc += __shfl_xor(cacc, 16, 64);                                     \
        cacc += __shfl_xor(cacc, 32, 64);                                     \
        if (lg == 0) ldsCol[(jtv) & 1][w][c * 16 + l15] = cacc;               \
      }                                                                       \
    }                                                                         \
  }

#define CRED(pt) (isSym && (q * KQ + (pt)) >= 4)

#define FLUSH(pt)                                                             \
  {                                                                           \
    float fv = ldsCol[(pt) & 1][0][lane] + ldsCol[(pt) & 1][1][lane] +        \
               ldsCol[(pt) & 1][2][lane] + ldsCol[(pt) & 1][3][lane];         \
    int fcol = TCOL(pt) * 64 + lane;                                          \
    if (useScratch)                                                           \
      scratch[(size_t)(sj * 32 + rb) * NR + fcol] = fv;                       \
    else                                                                      \
      atomicAdd(&out[fcol], fv);                                              \
  }

  // prologue: stage tile 0; A-frag loads fly under it; one full drain.
  STAGE(ldsbase, TCOL(0));

  // A fragments: row rowBase+m*16+l15, k-bytes [lg*32, lg*32+32)
  int32x8 af[4];
#pragma unroll
  for (int m = 0; m < 4; ++m)
    af[m] = *(const int32x8*)(A + (size_t)(rowBase + m * 16 + l15) * DD + lg * 32);

  float racc[4][4];
#pragma unroll
  for (int m = 0; m < 4; ++m)
#pragma unroll
    for (int j = 0; j < 4; ++j) racc[m][j] = 0.0f;

  asm volatile("s_waitcnt vmcnt(0)" ::: "memory");
  __builtin_amdgcn_s_barrier();
  __builtin_amdgcn_sched_barrier(0);

  // main loop: counted-vmcnt pipeline, ONE raw barrier per tile
  int cur = 0;
  for (int jt = 0; jt < nt - 1; ++jt) {
    int nxt = cur + 1; if (nxt == 3) nxt = 0;
    STAGE(ldsbase + nxt * 8192, TCOL(jt + 1));  // 2 loads stay in flight
    __builtin_amdgcn_sched_barrier(0);
    asm volatile("s_waitcnt vmcnt(2) lgkmcnt(0)" ::: "memory");
    __builtin_amdgcn_s_barrier();               // stage(jt) + ldsCol visible
    __builtin_amdgcn_sched_barrier(0);
    if (CRED(jt)) COMPUTE(ldsbase + cur * 8192, 1, jt)
    else          COMPUTE(ldsbase + cur * 8192, 0, jt);
    if (jt > 0 && CRED(jt - 1) && w == ((jt - 1) & 3)) FLUSH(jt - 1);
    cur = nxt;
  }
  // epilogue: tile nt-1
  __builtin_amdgcn_sched_barrier(0);
  asm volatile("s_waitcnt vmcnt(0) lgkmcnt(0)" ::: "memory");
  __builtin_amdgcn_s_barrier();
  __builtin_amdgcn_sched_barrier(0);
  if (CRED(nt - 1)) COMPUTE(ldsbase + cur * 8192, 1, nt - 1)
  else              COMPUTE(ldsbase + cur * 8192, 0, nt - 1);
  if (CRED(nt - 2) && w == ((nt - 2) & 3)) FLUSH(nt - 2);
  if (isSym) {
    asm volatile("s_waitcnt lgkmcnt(0)" ::: "memory");
    __builtin_amdgcn_s_barrier();
    if (CRED(nt - 1) && w == ((nt - 1) & 3)) FLUSH(nt - 1);
  }

  // row-sums: reduce over the 16 lanes (cols) in each lg group
#pragma unroll
  for (int off = 1; off < 16; off <<= 1)
#pragma unroll
    for (int m = 0; m < 4; ++m)
#pragma unroll
      for (int j = 0; j < 4; ++j)
        racc[m][j] += __shfl_xor(racc[m][j], off, 64);

  if (l15 == 0) {
#pragma unroll
    for (int m = 0; m < 4; ++m)
#pragma unroll
      for (int j = 0; j < 4; ++j)
        atomicAdd(&out[rowBase + m * 16 + lg * 4 + j], racc[m][j]);
  }
#undef STAGE
#undef COMPUTE
#undef CRED
#undef FLUSH
#undef TCOL
}

// ---------------------------------------------------------------------------
// K2b: reduce credit scratch [4][32][NR] -> credit [4][NR] (coalesced).
// ---------------------------------------------------------------------------
__global__ __launch_bounds__(256) void k_credit(
    const float* __restrict__ scratch, float* __restrict__ credit)
{
  int gid = blockIdx.x * 256 + threadIdx.x;   // 0..32767
  int s = gid >> 13, c = gid & (NR - 1);
  float t = 0.0f;
#pragma unroll 8
  for (int rb = 0; rb < 32; ++rb)
    t += scratch[(size_t)(s * 32 + rb) * NR + c];
  credit[s * NR + c] = t;
}

// ---------------------------------------------------------------------------
// K3: finalize.  16 rows per wave, one atomic per BLOCK (256 total).
// s11/s22 = atomic row-part + credit part.
// ---------------------------------------------------------------------------
__global__ __launch_bounds__(256) void k_finalize(
    const uint8_t* __restrict__ nb, const float* __restrict__ diag,
    const float* __restrict__ sums, const float* __restrict__ credit,
    int useScratch, float* __restrict__ out)
{
  __shared__ float part[4];
  int tid = threadIdx.x, w = tid >> 6, lane = tid & 63;
  int waveId = blockIdx.x * 4 + w;        // 0..1023
  float local = 0.0f;

  for (int i = 0; i < 16; ++i) {
    int rowId = waveId * 16 + i;          // 0..16383
    int p = rowId >> 13, r = rowId & (NR - 1);
    const uint8_t* n1 = nb + (size_t)(2 * p) * NR * DD + (size_t)r * DD;
    const uint8_t* n2 = n1 + (size_t)NR * DD;
    uint32_t a = *(const uint16_t*)(n1 + lane * 2);
    uint32_t b = *(const uint16_t*)(n2 + lane * 2);
    float a0 = dec_e4m3(a & 0xFFu), a1 = dec_e4m3(a >> 8);
    float b0 = dec_e4m3(b & 0xFFu), b1 = dec_e4m3(b >> 8);
    float p0 = EXP2F(a0 * b0) + EXP2F(a1 * b1);
#pragma unroll
    for (int off = 32; off >= 1; off >>= 1) p0 += __shfl_xor(p0, off, 64);

    if (lane == 0) {
      const float* s12v = sums + (3 * p) * NR;
      const float* s11v = sums + (3 * p + 1) * NR;
      const float* s22v = sums + (3 * p + 2) * NR;
      float cA = useScratch ? credit[(2 * p) * NR + r] : 0.0f;
      float cB = useScratch ? credit[(2 * p + 1) * NR + r] : 0.0f;
      float e1 = EXP2F(diag[(2 * p) * NR + r]);
      float e2 = EXP2F(diag[(2 * p + 1) * NR + r]);
      float s12 = s12v[r];
      float S1 = s12 + (s11v[r] + cA - e1) + p0;
      float S2 = s12 + (s22v[r] + cB - e2) + p0;
      local += logf(S1) + logf(S2) - 2.0f * logf(p0);
    }
  }
  if (lane == 0) part[w] = local;
  __syncthreads();
  if (tid == 0) {
    float t = part[0] + part[1] + part[2] + part[3];
    atomicAdd(out, 0.25f * t);
  }
}

// ---------------------------------------------------------------------------
extern "C" void kernel_launch(void* const* d_in, const int* in_sizes, int n_in,
                              void* d_out, int out_size, void* d_ws, size_t ws_size,
                              hipStream_t stream) {
  const float* u1 = (const float*)d_in[0];
  const float* u2 = (const float*)d_in[1];
  const float* i1 = (const float*)d_in[2];
  const float* i2 = (const float*)d_in[3];

  // ws: nb 4MB | diag[4][NR] | sums[6][NR] | scratch[4][32][NR] 4MB | credit[4][NR]
  uint8_t* nb = (uint8_t*)d_ws;
  float* diag = (float*)((char*)d_ws + (size_t)4 * NR * DD);
  float* sums = diag + 4 * NR;
  float* scratch = sums + 6 * NR;
  float* credit = scratch + (size_t)4 * 32 * NR;
  float* out = (float*)d_out;

  size_t need = (size_t)((char*)(credit + 4 * NR) - (char*)d_ws);
  int useScratch = (ws_size >= need) ? 1 : 0;
  int scrN = useScratch ? 4 * 32 * NR : 0;
  if (!useScratch) { scratch = sums; credit = sums; }  // valid dummies, unused

  k_normalize<<<NR * 4 / 4, 256, 0, stream>>>(u1, u2, i1, i2, nb, diag, sums,
                                              scratch, scrN, out);
  k_gram<<<1024, 256, 0, stream>>>(nb, sums, scratch, useScratch);
  if (useScratch) k_credit<<<128, 256, 0, stream>>>(scratch, credit);
  k_finalize<<<256, 256, 0, stream>>>(nb, diag, sums, credit, useScratch, out);
}